// Round 2
// baseline (180.018 us; speedup 1.0000x reference)
//
#include <hip/hip_runtime.h>

// mean(|box5(x) - box5(y)|), box5 = 5x5 uniform, pad=4.
// box(x)-box(y) = box(x-y), separable.
//
// Barrier-free: one WAVE owns a full 512-wide strip of R=4 output rows.
// Each lane owns 8 contiguous columns. Vertical 5-row rolling sum in
// registers (ring[5][8], compile-time indexed via full unroll). Horizontal
// 5-tap via 4 x __shfl_up per row. No LDS, no __syncthreads.
// R=4 -> 516/4 = 129 strips/image, 8256 waves = 32 waves/CU (HW max):
// latency-bound kernel, so maximize resident waves. The 2x row re-read
// amplification is absorbed by L3 (both inputs = 128 MB < 256 MB L3).

#define IMG_W 512
#define IMG_H 512
#define OUT_W 516
#define OUT_H 516
#define R     4              // output rows per wave strip (516 % 4 == 0)
#define SPI   (OUT_H / R)    // 129 strips per image
#define NT    256
#define WAVES (NT / 64)
#define NSTRIPS (64 * SPI)   // 8256 waves total
#define NPART 64             // partial-sum slots (atomic contention spread)

__global__ __launch_bounds__(NT) void box_loss_kernel(
    const float* __restrict__ x, const float* __restrict__ y,
    float* __restrict__ partial)
{
    const int t    = threadIdx.x;
    const int lane = t & 63;
    const int wid  = t >> 6;
    const int strip = blockIdx.x * WAVES + wid;     // 0..8255
    const int b  = strip / SPI;                     // batch image
    const int s  = strip - b * SPI;                 // strip in image
    const int i0 = s * R;                           // first output row
    const int c0 = lane * 8;                        // this lane's 8 columns

    const float* xb = x + (size_t)b * (IMG_W * IMG_H) + c0;
    const float* yb = y + (size_t)b * (IMG_W * IMG_H) + c0;

    // d-row history ring + vertical rolling sums, all in registers.
    float ring[5][8];
    float v[8];
    #pragma unroll
    for (int j = 0; j < 8; ++j) { v[j] = 0.f; ring[4][j] = 0.f; }

    // warm-up: input rows i0-4 .. i0-1 -> ring slots 0..3
    #pragma unroll
    for (int w = 0; w < 4; ++w) {
        const int r = i0 - 4 + w;
        float d[8] = {0.f, 0.f, 0.f, 0.f, 0.f, 0.f, 0.f, 0.f};
        if (r >= 0) {   // r <= i0-1 <= 511 always
            const float* xr = xb + (size_t)r * IMG_W;
            const float* yr = yb + (size_t)r * IMG_W;
            const float4 xa = *(const float4*)(xr);
            const float4 xc = *(const float4*)(xr + 4);
            const float4 ya = *(const float4*)(yr);
            const float4 yc = *(const float4*)(yr + 4);
            d[0] = xa.x - ya.x; d[1] = xa.y - ya.y;
            d[2] = xa.z - ya.z; d[3] = xa.w - ya.w;
            d[4] = xc.x - yc.x; d[5] = xc.y - yc.y;
            d[6] = xc.z - yc.z; d[7] = xc.w - yc.w;
        }
        #pragma unroll
        for (int j = 0; j < 8; ++j) { ring[w][j] = d[j]; v[j] += d[j]; }
    }

    float acc = 0.f;

    #pragma unroll
    for (int ii = 0; ii < R; ++ii) {
        const int i = i0 + ii;          // output row (wave-uniform), < 516

        // roll vertical window: add input row i (0 beyond image), drop i-5
        float d[8] = {0.f, 0.f, 0.f, 0.f, 0.f, 0.f, 0.f, 0.f};
        if (i < IMG_H) {
            const float* xr = xb + (size_t)i * IMG_W;
            const float* yr = yb + (size_t)i * IMG_W;
            const float4 xa = *(const float4*)(xr);
            const float4 xc = *(const float4*)(xr + 4);
            const float4 ya = *(const float4*)(yr);
            const float4 yc = *(const float4*)(yr + 4);
            d[0] = xa.x - ya.x; d[1] = xa.y - ya.y;
            d[2] = xa.z - ya.z; d[3] = xa.w - ya.w;
            d[4] = xc.x - yc.x; d[5] = xc.y - yc.y;
            d[6] = xc.z - yc.z; d[7] = xc.w - yc.w;
        }
        const int slot = (ii + 4) % 5;  // compile-time after unroll
        #pragma unroll
        for (int j = 0; j < 8; ++j) {
            v[j] += d[j] - ring[slot][j];
            ring[slot][j] = d[j];
        }

        // halo: previous lane's v[4..7] = vsum for cols c0-4..c0-1
        float h0 = __shfl_up(v[4], 1, 64);
        float h1 = __shfl_up(v[5], 1, 64);
        float h2 = __shfl_up(v[6], 1, 64);
        float h3 = __shfl_up(v[7], 1, 64);
        if (lane == 0) { h0 = 0.f; h1 = 0.f; h2 = 0.f; h3 = 0.f; }

        // sliding horizontal 5-tap over {h0..h3, v0..v7}
        const float s0 = h0 + h1 + h2 + h3 + v[0];
        const float s1 = s0 + v[1] - h0;
        const float s2 = s1 + v[2] - h1;
        const float s3 = s2 + v[3] - h2;
        const float s4 = s3 + v[4] - h3;
        const float s5 = s4 + v[5] - v[0];
        const float s6 = s5 + v[6] - v[1];
        const float s7 = s6 + v[7] - v[2];
        acc += fabsf(s0) + fabsf(s1) + fabsf(s2) + fabsf(s3)
             + fabsf(s4) + fabsf(s5) + fabsf(s6) + fabsf(s7);

        // right edge: output cols 512..515 (windows truncated by padding)
        if (lane == 63) {
            const float e0 = v[4] + v[5] + v[6] + v[7]; // out[512]
            const float e1 = v[5] + v[6] + v[7];        // out[513]
            const float e2 = v[6] + v[7];               // out[514]
            const float e3 = v[7];                      // out[515]
            acc += fabsf(e0) + fabsf(e1) + fabsf(e2) + fabsf(e3);
        }
    }

    // wave reduction, then one atomic per wave spread across 64 slots
    #pragma unroll
    for (int off = 32; off > 0; off >>= 1)
        acc += __shfl_down(acc, off, 64);
    if (lane == 0)
        atomicAdd(partial + (strip & (NPART - 1)), acc);
}

__global__ void finalize_kernel(const float* __restrict__ partial,
                                float* __restrict__ out)
{
    float s = 0.f;
    #pragma unroll
    for (int k = 0; k < NPART; ++k) s += partial[k];
    // each output scaled by 1/25 (uniform kernel), mean over 64*516*516
    out[0] = s * (1.0f / (25.0f * 64.0f * 516.0f * 516.0f));
}

extern "C" void kernel_launch(void* const* d_in, const int* in_sizes, int n_in,
                              void* d_out, int out_size, void* d_ws, size_t ws_size,
                              hipStream_t stream) {
    const float* x = (const float*)d_in[0];
    const float* y = (const float*)d_in[1];
    float* out = (float*)d_out;
    float* ws  = (float*)d_ws;

    hipMemsetAsync(ws, 0, NPART * sizeof(float), stream);

    dim3 grid(NSTRIPS / WAVES);   // 2064 blocks x 256 threads = 8256 waves
    box_loss_kernel<<<grid, NT, 0, stream>>>(x, y, ws);
    finalize_kernel<<<1, 1, 0, stream>>>(ws, out);
}

// Round 4
// 170.044 us; speedup vs baseline: 1.0587x; 1.0587x over previous
//
#include <hip/hip_runtime.h>

// mean(|box5(x) - box5(y)|), box5 = 5x5 uniform, pad=4.
// box(x)-box(y) = box(x-y), separable.
//
// Barrier-free: one WAVE owns a full 512-wide strip of R=8 output rows.
// Each lane owns 8 contiguous columns; vertical 5-row rolling sum in
// registers; horizontal 5-tap via 4 x __shfl_up per row.
//
// ALL loads are branch-free (row index clamped to [0,511], out-of-range
// contribution zeroed by an arithmetic mask). With the loop fully
// unrolled, the 48 float4 loads have no control dependence and the
// scheduler can hoist them deeply -> high per-wave MLP. Evidence: the
// branchy version had VGPR=32 (loads trapped behind branches, MLP~1,
// HBM stuck at 1.8 TB/s). Bijective XCD swizzle for L2-local halo reads.
//
// (Resubmission of round-3 source: previous bench died to a container
// infra failure, not a kernel fault — A/B vs round 2 still pending.)

#define IMG_W 512
#define IMG_H 512
#define OUT_W 516
#define OUT_H 516
#define R     8                  // output rows per wave strip
#define SPI   65                 // ceil(516/8)
#define NT    256
#define WAVES (NT / 64)
#define NSTRIPS (64 * SPI)       // 4160 waves
#define NBLK  (NSTRIPS / WAVES)  // 1040 blocks (130 per XCD)
#define NPART 64

__device__ __forceinline__ void load_row(const float* __restrict__ xb,
                                         const float* __restrict__ yb,
                                         int r, float d[8])
{
    // branch-free: clamp row, mask contribution
    const int   rc = min(max(r, 0), IMG_H - 1);
    const float m  = (r >= 0 && r < IMG_H) ? 1.f : 0.f;
    const float* xr = xb + (size_t)rc * IMG_W;
    const float* yr = yb + (size_t)rc * IMG_W;
    const float4 xa = *(const float4*)(xr);
    const float4 xc = *(const float4*)(xr + 4);
    const float4 ya = *(const float4*)(yr);
    const float4 yc = *(const float4*)(yr + 4);
    d[0] = (xa.x - ya.x) * m; d[1] = (xa.y - ya.y) * m;
    d[2] = (xa.z - ya.z) * m; d[3] = (xa.w - ya.w) * m;
    d[4] = (xc.x - yc.x) * m; d[5] = (xc.y - yc.y) * m;
    d[6] = (xc.z - yc.z) * m; d[7] = (xc.w - yc.w) * m;
}

__global__ __launch_bounds__(NT, 4) void box_loss_kernel(
    const float* __restrict__ x, const float* __restrict__ y,
    float* __restrict__ partial)
{
    const int t    = threadIdx.x;
    const int lane = t & 63;
    const int wid  = t >> 6;

    // bijective XCD swizzle: 1040 blocks -> 130 contiguous per XCD
    const int bid  = blockIdx.x;
    const int swz  = (bid & 7) * (NBLK / 8) + (bid >> 3);

    const int strip = swz * WAVES + wid;            // 0..4159
    const int b  = strip / SPI;                     // batch image
    const int s  = strip - b * SPI;                 // strip in image
    const int i0 = s * R;                           // first output row
    const int c0 = lane * 8;                        // this lane's 8 columns

    const float* xb = x + (size_t)b * (IMG_W * IMG_H) + c0;
    const float* yb = y + (size_t)b * (IMG_W * IMG_H) + c0;

    // d-row history ring + vertical rolling sums, all in registers.
    float ring[5][8];
    float v[8];
    #pragma unroll
    for (int j = 0; j < 8; ++j) { v[j] = 0.f; ring[4][j] = 0.f; }

    // warm-up: input rows i0-4 .. i0-1 -> ring slots 0..3 (branch-free)
    #pragma unroll
    for (int w = 0; w < 4; ++w) {
        float d[8];
        load_row(xb, yb, i0 - 4 + w, d);
        #pragma unroll
        for (int j = 0; j < 8; ++j) { ring[w][j] = d[j]; v[j] += d[j]; }
    }

    float acc = 0.f;

    #pragma unroll
    for (int ii = 0; ii < R; ++ii) {
        const int i = i0 + ii;              // output row (wave-uniform)

        // roll vertical window: add input row i (masked), drop row i-5
        float d[8];
        load_row(xb, yb, i, d);
        const int slot = (ii + 4) % 5;      // compile-time after unroll
        #pragma unroll
        for (int j = 0; j < 8; ++j) {
            v[j] += d[j] - ring[slot][j];
            ring[slot][j] = d[j];
        }

        // halo: previous lane's v[4..7] = vsums for cols c0-4..c0-1
        float h0 = __shfl_up(v[4], 1, 64);
        float h1 = __shfl_up(v[5], 1, 64);
        float h2 = __shfl_up(v[6], 1, 64);
        float h3 = __shfl_up(v[7], 1, 64);
        if (lane == 0) { h0 = 0.f; h1 = 0.f; h2 = 0.f; h3 = 0.f; }

        // sliding horizontal 5-tap over {h0..h3, v0..v7}
        const float s0 = h0 + h1 + h2 + h3 + v[0];
        const float s1 = s0 + v[1] - h0;
        const float s2 = s1 + v[2] - h1;
        const float s3 = s2 + v[3] - h2;
        const float s4 = s3 + v[4] - h3;
        const float s5 = s4 + v[5] - v[0];
        const float s6 = s5 + v[6] - v[1];
        const float s7 = s6 + v[7] - v[2];

        const float rowmask = (i < OUT_H) ? 1.f : 0.f;  // ragged last strip
        acc += rowmask * (fabsf(s0) + fabsf(s1) + fabsf(s2) + fabsf(s3)
                        + fabsf(s4) + fabsf(s5) + fabsf(s6) + fabsf(s7));

        // right edge: output cols 512..515 (windows truncated by padding)
        const float em = (lane == 63) ? rowmask : 0.f;
        const float e0 = v[4] + v[5] + v[6] + v[7];
        const float e1 = v[5] + v[6] + v[7];
        const float e2 = v[6] + v[7];
        const float e3 = v[7];
        acc += em * (fabsf(e0) + fabsf(e1) + fabsf(e2) + fabsf(e3));
    }

    // wave reduction, then one atomic per wave spread across 64 slots
    #pragma unroll
    for (int off = 32; off > 0; off >>= 1)
        acc += __shfl_down(acc, off, 64);
    if (lane == 0)
        atomicAdd(partial + (strip & (NPART - 1)), acc);
}

__global__ void finalize_kernel(const float* __restrict__ partial,
                                float* __restrict__ out)
{
    float s = 0.f;
    #pragma unroll
    for (int k = 0; k < NPART; ++k) s += partial[k];
    // each output scaled by 1/25 (uniform kernel), mean over 64*516*516
    out[0] = s * (1.0f / (25.0f * 64.0f * 516.0f * 516.0f));
}

extern "C" void kernel_launch(void* const* d_in, const int* in_sizes, int n_in,
                              void* d_out, int out_size, void* d_ws, size_t ws_size,
                              hipStream_t stream) {
    const float* x = (const float*)d_in[0];
    const float* y = (const float*)d_in[1];
    float* out = (float*)d_out;
    float* ws  = (float*)d_ws;

    hipMemsetAsync(ws, 0, NPART * sizeof(float), stream);

    dim3 grid(NBLK);   // 1040 blocks x 256 threads = 4160 waves
    box_loss_kernel<<<grid, NT, 0, stream>>>(x, y, ws);
    finalize_kernel<<<1, 1, 0, stream>>>(ws, out);
}